// Round 6
// baseline (520.359 us; speedup 1.0000x reference)
//
#include <hip/hip_runtime.h>
#include <hip/hip_bf16.h>

#define B_   32
#define L_   2048
#define CIN  256
#define HID  512
#define TL   32
#define NLT  (L_ / TL)        // 64 tiles of 32 rows per batch
#define NTILES (B_ * NLT)     // 2048
#define NBLK  256             // persistent: 1 block per CU
#define TPB   (NTILES / NBLK) // 8 tiles per block

typedef __bf16 bf16_t;
typedef __bf16 bf16x8 __attribute__((ext_vector_type(8)));
typedef __bf16 bf16x4 __attribute__((ext_vector_type(4)));
typedef float  f32x4  __attribute__((ext_vector_type(4)));

// LDS map (128 KB): A double-buffer 4x16KB, then H 2x32KB
//   buf b, pipeline p (0=x,1=y): A @ b*32768 + p*16384
#define A_OFF(buf, p) ((unsigned)((buf) * 32768 + (p) * 16384))
#define HX_OFF 65536u
#define HY_OFF 98304u

__device__ __forceinline__ float fast_tanh(float v) {
    float x = fminf(fmaxf(v, -9.0f), 9.0f);
    float e = exp2f(x * 2.885390081777927f);           // e^{2x}
    return (e - 1.0f) * __builtin_amdgcn_rcpf(e + 1.0f);
}

// ---------------------------------------------------------------------------
// Kernel 1: cast weights fp32 -> bf16 into workspace
// ---------------------------------------------------------------------------
__global__ void cast_weights_kernel(const float* __restrict__ W1, const float* __restrict__ W2,
                                    bf16_t* __restrict__ W1b, bf16_t* __restrict__ W2b)
{
    int i = blockIdx.x * blockDim.x + threadIdx.x;
    if (i < HID * CIN) W1b[i] = (bf16_t)W1[i];
    if (i < HID * HID) W2b[i] = (bf16_t)W2[i];
}

// ---------------------------------------------------------------------------
// Kernel 2: persistent fused kernel. 256 blocks (1/CU) x 1024 threads
// (16 waves). Each block processes 8 consecutive 32-row tiles, pipelined:
// tile t+1's x/y global loads are issued (into regs) at the top of iter t
// and written to the A double-buffer after writeH -> HBM latency hides under
// gemm1+writeH; weights stay XCD-L2 resident across the 8 tiles.
// Wave w owns 32 cols; acc = 32 AGPR; arch regs ~70 < 96 cap (no spill).
// 2 barriers per tile.
// ---------------------------------------------------------------------------
__global__ __launch_bounds__(1024, 4)
void fused_proj_kernel(const float* __restrict__ x, const float* __restrict__ y,
                       const bf16_t* __restrict__ W1b, const float* __restrict__ b1,
                       const bf16_t* __restrict__ W2b, const float* __restrict__ b2,
                       float* __restrict__ partial)
{
    __shared__ char U[131072];           // 128 KB

    const int tid  = threadIdx.x;
    const int lane = tid & 63;
    const int wv   = tid >> 6;           // wave 0..15
    const int l15  = lane & 15;
    const int l4   = lane >> 4;
    const int col0 = wv * 32;            // this wave's output-col base

    // staging role: threads 0-511 stage x, 512-1023 stage y; 16 threads/row
    const int sp  = tid >> 9;            // 0 -> x, 1 -> y
    const int t9  = tid & 511;
    const int sr  = t9 >> 4;             // row 0..31
    const int sq  = t9 & 15;             // float4 group within row
    const float* sbase = sp ? y : x;
    const unsigned sswz = (unsigned)((sr & 15) << 4);

    float bias1[2], bias2[2];
#pragma unroll
    for (int j = 0; j < 2; ++j) {
        bias1[j] = b1[col0 + j * 16 + l15];
        bias2[j] = b2[col0 + j * 16 + l15];
    }

    // Precomputed swizzled LDS read offsets; per-kk address = base ^ (kk<<6)
    // (row-stride bits >= 9/10 are disjoint from kk bits 6..9, and the
    // kk*64 + l4*16 add is disjoint-bit, so XOR == the swizzled sum).
    unsigned aoff[2], hoff[2];
#pragma unroll
    for (int i = 0; i < 2; ++i) {
        const int r = i * 16 + l15;
        const unsigned swz = (unsigned)((r & 15) << 4);
        aoff[i] = (unsigned)(r * (CIN * 2)) + (((unsigned)(l4 * 16)) ^ swz);
        hoff[i] = (unsigned)(r * (HID * 2)) + (((unsigned)(l4 * 16)) ^ swz);
    }

    const int tile0 = blockIdx.x * TPB;

    // issue global loads for a tile (4 float4 per thread, coalesced)
    auto load_tile = [&](int tile, float4 (&v)[4]) {
        const int bb = tile >> 6;        // batch
        const int lt = tile & 63;        // l-tile
        const float4* s4 = reinterpret_cast<const float4*>(
            sbase + ((size_t)bb * L_ + (size_t)lt * TL + sr) * CIN);
#pragma unroll
        for (int c = 0; c < 4; ++c)
            v[c] = s4[sq + 16 * c];
    };
    // cvt + write staged regs into A buffer (swizzled)
    auto store_tile = [&](int buf, float4 (&v)[4]) {
        char* rowp = U + A_OFF(buf, sp) + sr * (CIN * 2);
#pragma unroll
        for (int c = 0; c < 4; ++c) {
            const int f = sq + 16 * c;
            bf16x4 h;
            h[0] = (bf16_t)v[c].x; h[1] = (bf16_t)v[c].y;
            h[2] = (bf16_t)v[c].z; h[3] = (bf16_t)v[c].w;
            *reinterpret_cast<bf16x4*>(rowp + (((unsigned)(8 * f)) ^ sswz)) = h;
        }
    };

    float4 v[4];
    load_tile(tile0, v);
    store_tile(0, v);
    __syncthreads();                     // A buf0 ready

    int cur = 0;
    for (int t = 0; t < TPB; ++t) {
        const int tile = tile0 + t;
        if (t + 1 < TPB) load_tile(tile + 1, v);   // issue early (T14)

        f32x4 accx[2][2], accy[2][2];
#pragma unroll
        for (int i = 0; i < 2; ++i)
#pragma unroll
            for (int j = 0; j < 2; ++j) {
                accx[i][j] = (f32x4){0.f, 0.f, 0.f, 0.f};
                accy[i][j] = (f32x4){0.f, 0.f, 0.f, 0.f};
            }

        // --- GEMM1 (x,y share the W1 stream)
        for (int kk = 0; kk < CIN / 32; ++kk) {
            bf16x8 w[2];
#pragma unroll
            for (int j = 0; j < 2; ++j) {
                int cc = col0 + j * 16 + l15;
                w[j] = *reinterpret_cast<const bf16x8*>(W1b + (size_t)cc * CIN + kk * 32 + l4 * 8);
            }
#pragma unroll
            for (int i = 0; i < 2; ++i) {
                unsigned o = aoff[i] ^ (unsigned)(kk << 6);
                bf16x8 ax = *reinterpret_cast<const bf16x8*>(U + A_OFF(cur, 0) + o);
                bf16x8 ay = *reinterpret_cast<const bf16x8*>(U + A_OFF(cur, 1) + o);
#pragma unroll
                for (int j = 0; j < 2; ++j) {
                    accx[i][j] = __builtin_amdgcn_mfma_f32_16x16x32_bf16(ax, w[j], accx[i][j], 0, 0, 0);
                    accy[i][j] = __builtin_amdgcn_mfma_f32_16x16x32_bf16(ay, w[j], accy[i][j], 0, 0, 0);
                }
            }
        }

        // --- write H1 = acc + b1 (bf16, swizzled). H readers of tile t-1
        // finished at the end-of-iter barrier, so no barrier needed here.
#pragma unroll
        for (int i = 0; i < 2; ++i)
#pragma unroll
            for (int j = 0; j < 2; ++j) {
                unsigned colb = (unsigned)((col0 + j * 16 + l15) * 2);
#pragma unroll
                for (int r2 = 0; r2 < 4; ++r2) {
                    int r = i * 16 + l4 * 4 + r2;
                    unsigned off = (unsigned)(r * (HID * 2)) + (colb ^ ((unsigned)((r & 15) << 4)));
                    *reinterpret_cast<bf16_t*>(U + HX_OFF + off) = (bf16_t)(accx[i][j][r2] + bias1[j]);
                    *reinterpret_cast<bf16_t*>(U + HY_OFF + off) = (bf16_t)(accy[i][j][r2] + bias1[j]);
                }
            }

        if (t + 1 < TPB) store_tile(cur ^ 1, v);   // write-late into other buf

        __syncthreads();                 // H ready + A[next] ready

        // --- GEMM2 (x,y share the W2 stream)
#pragma unroll
        for (int i = 0; i < 2; ++i)
#pragma unroll
            for (int j = 0; j < 2; ++j) {
                accx[i][j] = (f32x4){0.f, 0.f, 0.f, 0.f};
                accy[i][j] = (f32x4){0.f, 0.f, 0.f, 0.f};
            }
        for (int kk = 0; kk < HID / 32; ++kk) {
            bf16x8 w[2];
#pragma unroll
            for (int j = 0; j < 2; ++j) {
                int cc = col0 + j * 16 + l15;
                w[j] = *reinterpret_cast<const bf16x8*>(W2b + (size_t)cc * HID + kk * 32 + l4 * 8);
            }
#pragma unroll
            for (int i = 0; i < 2; ++i) {
                unsigned o = hoff[i] ^ (unsigned)(kk << 6);
                bf16x8 ax = *reinterpret_cast<const bf16x8*>(U + HX_OFF + o);
                bf16x8 ay = *reinterpret_cast<const bf16x8*>(U + HY_OFF + o);
#pragma unroll
                for (int j = 0; j < 2; ++j) {
                    accx[i][j] = __builtin_amdgcn_mfma_f32_16x16x32_bf16(ax, w[j], accx[i][j], 0, 0, 0);
                    accy[i][j] = __builtin_amdgcn_mfma_f32_16x16x32_bf16(ay, w[j], accy[i][j], 0, 0, 0);
                }
            }
        }
        __syncthreads();                 // all H + A[cur] reads done

        // --- tanh product + row-reduction (register-only) + partial store
        float colsum[2] = {0.f, 0.f};
#pragma unroll
        for (int i = 0; i < 2; ++i)
#pragma unroll
            for (int j = 0; j < 2; ++j)
#pragma unroll
                for (int r2 = 0; r2 < 4; ++r2) {
                    float tx = fast_tanh(accx[i][j][r2] + bias2[j]);
                    float ty = fast_tanh(accy[i][j][r2] + bias2[j]);
                    colsum[j] += tx * ty;
                }
#pragma unroll
        for (int j = 0; j < 2; ++j) {
            colsum[j] += __shfl_xor(colsum[j], 16);
            colsum[j] += __shfl_xor(colsum[j], 32);
        }
        if (lane < 16) {
#pragma unroll
            for (int j = 0; j < 2; ++j)
                partial[(size_t)tile * HID + col0 + j * 16 + lane] = colsum[j];
        }
        cur ^= 1;
    }
}

// ---------------------------------------------------------------------------
// Kernel 3: sum the 64 l-tile partials per batch -> out[B][HID]
// ---------------------------------------------------------------------------
__global__ void reduce_kernel(const float* __restrict__ partial, float* __restrict__ out)
{
    int b = blockIdx.x;
    int g = threadIdx.x;             // 512 threads
    float s = 0.f;
#pragma unroll
    for (int t = 0; t < NLT; ++t)
        s += partial[((size_t)(b * NLT + t)) * HID + g];
    out[b * HID + g] = s;
}

extern "C" void kernel_launch(void* const* d_in, const int* in_sizes, int n_in,
                              void* d_out, int out_size, void* d_ws, size_t ws_size,
                              hipStream_t stream)
{
    const float* x  = (const float*)d_in[0];
    const float* y  = (const float*)d_in[1];
    const float* W1 = (const float*)d_in[2];
    const float* b1 = (const float*)d_in[3];
    const float* W2 = (const float*)d_in[4];
    const float* b2 = (const float*)d_in[5];
    float* out = (float*)d_out;

    char* ws = (char*)d_ws;
    bf16_t* W1b    = (bf16_t*)ws;                    // 256 KB
    bf16_t* W2b    = (bf16_t*)(ws + (256 << 10));    // 512 KB
    float*  partial = (float*)(ws + (768 << 10));    // 4 MB (2048 tiles x 512)

    hipLaunchKernelGGL(cast_weights_kernel, dim3(1024), dim3(256), 0, stream, W1, W2, W1b, W2b);
    hipLaunchKernelGGL(fused_proj_kernel, dim3(NBLK), dim3(1024), 0, stream,
                       x, y, W1b, b1, W2b, b2, partial);
    hipLaunchKernelGGL(reduce_kernel, dim3(B_), dim3(512), 0, stream, partial, out);
}

// Round 7
// 147.774 us; speedup vs baseline: 3.5213x; 3.5213x over previous
//
#include <hip/hip_runtime.h>
#include <hip/hip_bf16.h>

#define B_   32
#define L_   2048
#define CIN  256
#define HID  512
#define TL   64
#define NLT  (L_ / TL)   // 32 l-tiles per batch

typedef __bf16 bf16_t;
typedef __bf16 bf16x8 __attribute__((ext_vector_type(8)));
typedef __bf16 bf16x4 __attribute__((ext_vector_type(4)));
typedef float  f32x4  __attribute__((ext_vector_type(4)));

// LDS map (128 KB): A(x)@0 32K, A(y)@64K 32K; alias H(x)@0 64K, H(y)@64K 64K
#define AX_OFF 0u
#define AY_OFF 65536u
#define HX_OFF 0u
#define HY_OFF 65536u

// ---------------------------------------------------------------------------
// Kernel 1: cast weights fp32 -> bf16 into workspace
// ---------------------------------------------------------------------------
__global__ void cast_weights_kernel(const float* __restrict__ W1, const float* __restrict__ W2,
                                    bf16_t* __restrict__ W1b, bf16_t* __restrict__ W2b)
{
    int i = blockIdx.x * blockDim.x + threadIdx.x;
    if (i < HID * CIN) W1b[i] = (bf16_t)W1[i];
    if (i < HID * HID) W2b[i] = (bf16_t)W2[i];
}

// ---------------------------------------------------------------------------
// Kernel 2: fused project(x)+project(y), tanh*tanh, partial row-reduction.
// R4 base (1024 thr, 16 waves, 64-row tile, 32 cols/wave, 1 tile/block) with
// SWAPPED MFMA operands: acc = mfma(W-frag, x-frag, acc), so D.m = H-col and
// each lane holds 4 consecutive H-cols -> writeH is ds_write_b64 (4x fewer
// LDS ops). Biases folded into acc init. Paired tanh (1 rcp per pair).
// Register ledger (the R2/R5/R6 lesson): 64 AGPR acc + ~60 arch <= 128 total
// at the 4-wave/SIMD cap forced by the 1024-thread block. No new live state.
// ---------------------------------------------------------------------------
__global__ __launch_bounds__(1024, 4)
void fused_proj_kernel(const float* __restrict__ x, const float* __restrict__ y,
                       const bf16_t* __restrict__ W1b, const float* __restrict__ b1,
                       const bf16_t* __restrict__ W2b, const float* __restrict__ b2,
                       float* __restrict__ partial)
{
    __shared__ char U[131072];           // 128 KB

    const int tid  = threadIdx.x;
    const int lane = tid & 63;
    const int wv   = tid >> 6;           // wave 0..15
    const int l15  = lane & 15;
    const int l4   = lane >> 4;
    const int blk  = blockIdx.x;
    const int b    = blk >> 5;           // batch
    const int lt   = blk & 31;           // l-tile
    const int col0 = wv * 32;            // this wave's output-col base

    const float* xrows = x + ((size_t)(b * L_) + (size_t)lt * TL) * CIN;
    const float* yrows = y + ((size_t)(b * L_) + (size_t)lt * TL) * CIN;

    // --- stage: threads 0-511 stage x -> A(x), 512-1023 stage y -> A(y)
    {
        const int t = tid & 511;
        const float* src = (tid < 512) ? xrows : yrows;
        const unsigned base = (tid < 512) ? AX_OFF : AY_OFF;
        const int r = t >> 3;            // 64 rows, 8 threads/row
        const int q = t & 7;
        const float4* srow = reinterpret_cast<const float4*>(src + (size_t)r * CIN);
        char* rowp = U + base + r * (CIN * 2);
        const unsigned swz = (unsigned)((r & 15) << 4);
#pragma unroll
        for (int c = 0; c < 8; ++c) {
            const int f = q + 8 * c;     // float4 index within row (coalesced)
            float4 v = srow[f];
            bf16x4 h;
            h[0] = (bf16_t)v.x; h[1] = (bf16_t)v.y; h[2] = (bf16_t)v.z; h[3] = (bf16_t)v.w;
            *reinterpret_cast<bf16x4*>(rowp + (((unsigned)(8 * f)) ^ swz)) = h;
        }
    }
    __syncthreads();                     // A(x), A(y) ready

    // acc[ri][cj]: rows ri*16+l15 (n-dim), H-cols col0+cj*16+l4*4+r2 (m-dim).
    f32x4 hx[4][2], hy[4][2];
    {
#pragma unroll
        for (int cj = 0; cj < 2; ++cj) {
            float4 bv = *reinterpret_cast<const float4*>(b1 + col0 + cj * 16 + l4 * 4);
            f32x4 bi = (f32x4){bv.x, bv.y, bv.z, bv.w};
#pragma unroll
            for (int ri = 0; ri < 4; ++ri) { hx[ri][cj] = bi; hy[ri][cj] = bi; }
        }
    }

    // --- GEMM1 (swapped: W is the A-operand; x,y share the W1 stream)
    for (int kk = 0; kk < CIN / 32; ++kk) {
        bf16x8 w[2];
#pragma unroll
        for (int cj = 0; cj < 2; ++cj) {
            int cc = col0 + cj * 16 + l15;
            w[cj] = *reinterpret_cast<const bf16x8*>(W1b + (size_t)cc * CIN + kk * 32 + l4 * 8);
        }
        __builtin_amdgcn_s_setprio(1);
#pragma unroll
        for (int ri = 0; ri < 4; ++ri) {
            int r = ri * 16 + l15;
            unsigned off = (unsigned)(r * (CIN * 2)) +
                           (((unsigned)(kk * 64 + l4 * 16)) ^ ((unsigned)((r & 15) << 4)));
            bf16x8 ax = *reinterpret_cast<const bf16x8*>(U + AX_OFF + off);
            bf16x8 ay = *reinterpret_cast<const bf16x8*>(U + AY_OFF + off);
#pragma unroll
            for (int cj = 0; cj < 2; ++cj) {
                hx[ri][cj] = __builtin_amdgcn_mfma_f32_16x16x32_bf16(w[cj], ax, hx[ri][cj], 0, 0, 0);
                hy[ri][cj] = __builtin_amdgcn_mfma_f32_16x16x32_bf16(w[cj], ay, hy[ri][cj], 0, 0, 0);
            }
        }
        __builtin_amdgcn_s_setprio(0);
    }
    __syncthreads();                     // all A reads done (H clobbers A)

    // --- write H1 (bias already in acc) as packed bf16x4 (ds_write_b64)
#pragma unroll
    for (int ri = 0; ri < 4; ++ri) {
        const int r = ri * 16 + l15;
        const unsigned swz = (unsigned)((r & 15) << 4);
#pragma unroll
        for (int cj = 0; cj < 2; ++cj) {
            unsigned off = (unsigned)(r * (HID * 2)) +
                           (((unsigned)((col0 + cj * 16 + l4 * 4) * 2)) ^ swz);
            bf16x4 px, py;
#pragma unroll
            for (int r2 = 0; r2 < 4; ++r2) {
                px[r2] = (bf16_t)hx[ri][cj][r2];
                py[r2] = (bf16_t)hy[ri][cj][r2];
            }
            *reinterpret_cast<bf16x4*>(U + HX_OFF + off) = px;
            *reinterpret_cast<bf16x4*>(U + HY_OFF + off) = py;
        }
    }
    __syncthreads();                     // H(x), H(y) ready

    {
#pragma unroll
        for (int cj = 0; cj < 2; ++cj) {
            float4 bv = *reinterpret_cast<const float4*>(b2 + col0 + cj * 16 + l4 * 4);
            f32x4 bi = (f32x4){bv.x, bv.y, bv.z, bv.w};
#pragma unroll
            for (int ri = 0; ri < 4; ++ri) { hx[ri][cj] = bi; hy[ri][cj] = bi; }
        }
    }

    // --- GEMM2 (swapped; x,y share the W2 stream)
    for (int kk = 0; kk < HID / 32; ++kk) {
        bf16x8 w[2];
#pragma unroll
        for (int cj = 0; cj < 2; ++cj) {
            int cc = col0 + cj * 16 + l15;
            w[cj] = *reinterpret_cast<const bf16x8*>(W2b + (size_t)cc * HID + kk * 32 + l4 * 8);
        }
        __builtin_amdgcn_s_setprio(1);
#pragma unroll
        for (int ri = 0; ri < 4; ++ri) {
            int r = ri * 16 + l15;
            unsigned off = (unsigned)(r * (HID * 2)) +
                           (((unsigned)(kk * 64 + l4 * 16)) ^ ((unsigned)((r & 15) << 4)));
            bf16x8 px = *reinterpret_cast<const bf16x8*>(U + HX_OFF + off);
            bf16x8 py = *reinterpret_cast<const bf16x8*>(U + HY_OFF + off);
#pragma unroll
            for (int cj = 0; cj < 2; ++cj) {
                hx[ri][cj] = __builtin_amdgcn_mfma_f32_16x16x32_bf16(w[cj], px, hx[ri][cj], 0, 0, 0);
                hy[ri][cj] = __builtin_amdgcn_mfma_f32_16x16x32_bf16(w[cj], py, hy[ri][cj], 0, 0, 0);
            }
        }
        __builtin_amdgcn_s_setprio(0);
    }

    // --- paired tanh product + row reduction.
    // tanh(a)*tanh(b) = (Ea-1)(Eb-1) / ((Ea+1)(Eb+1)),  E = e^{2v} (clamped).
    f32x4 psum[2];
    psum[0] = (f32x4){0.f, 0.f, 0.f, 0.f};
    psum[1] = (f32x4){0.f, 0.f, 0.f, 0.f};
#pragma unroll
    for (int ri = 0; ri < 4; ++ri)
#pragma unroll
        for (int cj = 0; cj < 2; ++cj)
#pragma unroll
            for (int r2 = 0; r2 < 4; ++r2) {
                float a = fminf(fmaxf(hx[ri][cj][r2], -9.0f), 9.0f);
                float c = fminf(fmaxf(hy[ri][cj][r2], -9.0f), 9.0f);
                float Ea = exp2f(a * 2.885390081777927f);
                float Eb = exp2f(c * 2.885390081777927f);
                float num = (Ea - 1.0f) * (Eb - 1.0f);
                float den = (Ea + 1.0f) * (Eb + 1.0f);
                psum[cj][r2] += num * __builtin_amdgcn_rcpf(den);
            }
    // rows live in l15 (16 lanes) x ri (summed): reduce across l15 bits
#pragma unroll
    for (int cj = 0; cj < 2; ++cj)
#pragma unroll
        for (int r2 = 0; r2 < 4; ++r2) {
            float s = psum[cj][r2];
            s += __shfl_xor(s, 1);
            s += __shfl_xor(s, 2);
            s += __shfl_xor(s, 4);
            s += __shfl_xor(s, 8);
            psum[cj][r2] = s;
        }
    if (l15 == 0) {
#pragma unroll
        for (int cj = 0; cj < 2; ++cj) {
            float4 o = make_float4(psum[cj][0], psum[cj][1], psum[cj][2], psum[cj][3]);
            *reinterpret_cast<float4*>(partial + (size_t)blk * HID + col0 + cj * 16 + l4 * 4) = o;
        }
    }
}

// ---------------------------------------------------------------------------
// Kernel 3: sum the 32 l-tile partials per batch -> out[B][HID]
// ---------------------------------------------------------------------------
__global__ void reduce_kernel(const float* __restrict__ partial, float* __restrict__ out)
{
    int b = blockIdx.x;
    int g = threadIdx.x;             // 512 threads
    float s = 0.f;
#pragma unroll
    for (int t = 0; t < NLT; ++t)
        s += partial[((size_t)(b * NLT + t)) * HID + g];
    out[b * HID + g] = s;
}

extern "C" void kernel_launch(void* const* d_in, const int* in_sizes, int n_in,
                              void* d_out, int out_size, void* d_ws, size_t ws_size,
                              hipStream_t stream)
{
    const float* x  = (const float*)d_in[0];
    const float* y  = (const float*)d_in[1];
    const float* W1 = (const float*)d_in[2];
    const float* b1 = (const float*)d_in[3];
    const float* W2 = (const float*)d_in[4];
    const float* b2 = (const float*)d_in[5];
    float* out = (float*)d_out;

    char* ws = (char*)d_ws;
    bf16_t* W1b    = (bf16_t*)ws;                    // 256 KB
    bf16_t* W2b    = (bf16_t*)(ws + (256 << 10));    // 512 KB
    float*  partial = (float*)(ws + (768 << 10));    // 2 MB (1024 blocks x 512)

    hipLaunchKernelGGL(cast_weights_kernel, dim3(1024), dim3(256), 0, stream, W1, W2, W1b, W2b);
    hipLaunchKernelGGL(fused_proj_kernel, dim3(B_ * NLT), dim3(1024), 0, stream,
                       x, y, W1b, b1, W2b, b2, partial);
    hipLaunchKernelGGL(reduce_kernel, dim3(B_), dim3(512), 0, stream, partial, out);
}